// Round 1
// 157.950 us; speedup vs baseline: 1.0514x; 1.0514x over previous
//
#include <hip/hip_runtime.h>
#include <math.h>

#define KDIM 128
#define TLEN 512
#define BATCH 16
#define CH_L 16
#define NCH 32           // chunks per batch (replay)
#define NMAT 31          // chunk matrices: chunk c covers t in [16c+1, 16c+16]

typedef _Float16 half8 __attribute__((ext_vector_type(8)));
typedef _Float16 half4 __attribute__((ext_vector_type(4)));
typedef _Float16 half2t __attribute__((ext_vector_type(2)));
typedef float floatx4 __attribute__((ext_vector_type(4)));

#if defined(__has_builtin)
#if __has_builtin(__builtin_amdgcn_fdot2)
#define HAVE_FDOT2 1
#endif
#endif

static __device__ __forceinline__ float dot2f(half2t a, half2t b, float c) {
#ifdef HAVE_FDOT2
    return __builtin_amdgcn_fdot2(a, b, c, false);
#else
    return fmaf((float)a[0], (float)b[0], fmaf((float)a[1], (float)b[1], c));
#endif
}

// acc += dot(packed-f16 w (4 VGPRs = 8 halfs), half8 v)
static __device__ __forceinline__ float dot8(const half8 v, const float4 w, float acc) {
    const uint4 r = __builtin_bit_cast(uint4, v);
    acc = dot2f(__builtin_bit_cast(half2t, w.x), __builtin_bit_cast(half2t, r.x), acc);
    acc = dot2f(__builtin_bit_cast(half2t, w.y), __builtin_bit_cast(half2t, r.y), acc);
    acc = dot2f(__builtin_bit_cast(half2t, w.z), __builtin_bit_cast(half2t, r.z), acc);
    acc = dot2f(__builtin_bit_cast(half2t, w.w), __builtin_bit_cast(half2t, r.w), acc);
    return acc;
}

// async global->LDS, 16 B per lane; LDS dest = wave-uniform base + lane*16
static __device__ __forceinline__ void gload_lds16(const _Float16* g, _Float16* l) {
    __builtin_amdgcn_global_load_lds(
        (const __attribute__((address_space(1))) void*)g,
        (__attribute__((address_space(3))) void*)l, 16, 0, 0);
}

// ---------------- workspace layouts (bytes) ----------------
// NEW path: per-column (enter-state) scale vectors instead of scalar S.
#define WSN_PST   0               // f16 [BATCH][NMAT][16384]
#define WSN_SVEC  16252928        // f32 [BATCH][NMAT][128] column log-scales
#define WSN_AENT  16506880        // f32 [BATCH][NCH][128]
#define WSN_NEED  16769024
// OLD path (kept as hedge if ws is tight): scalar S per chunk.
#define WSO_PST   0
#define WSO_SLOG  16252928
#define WSO_AENT  16254912
#define WSO_NEED  16517056

// Frag conventions (validated R2-R12 of previous session):
//  A-frag tile(mt,kt): lane(quad,lm) holds A[mt*16+lm][kt*32+quad*8 .. +8]
//  B-frag tile(kt,nt): lane(quad,lm) holds B[kt*32+quad*8 .. +8][nt*16+lm]
//  C/D  tile(mt,nt):   lane(quad,lm) reg q = C[mt*16+quad*4+q][nt*16+lm]
//
// ============ kernel 1 (NEW): column-parallel, barrier-free chunk products =====
// Each wave owns 32 enter-columns of the running product P[m=exit][n=enter].
// B operand (P[k][own n]) lives in registers (8 frags = 32 VGPRs); F=exp(trans^T)
// is constant, staged once in LDS, re-read as A-frags each iteration.
// Rescale is PER COLUMN (wave-local: 2 shfl_xor) -> zero barriers after staging,
// no cross-wave traffic, no global-max serialization. Per-column log-scales go
// to Svec and are folded into the scan's p-vector (strictly better f16
// conditioning than the old global scalar).
// LDS: Flds 34,816 + Wscr 4x9,216 + gAll 8,192 = 79,872 B -> 2 blocks/CU.
__global__ __launch_bounds__(256, 2) void crf_chunkcols(
    const float* __restrict__ trans, const float* __restrict__ em,
    _Float16* __restrict__ Pst, float* __restrict__ Svec)
{
    const int c = blockIdx.x;     // 0..NMAT-1
    const int b = blockIdx.y;
    const int tid = threadIdx.x;
    const int w = tid >> 6, lane = tid & 63;
    const int quad = lane >> 4, lm = lane & 15;

    // F[m][k] = exp(trans[k][m]); row stride 136 halfs (272B: 16B-aligned,
    // A-reads land 2 lanes/bank = free).
    __shared__ __align__(16) _Float16 Flds[128 * 136];   // 34,816 B
    // Per-wave scratch: iterations use B-layout [n][m] stride 136 (4352 halfs);
    // final iteration uses T-layout [m][n_local] stride 36 (4608 halfs).
    __shared__ __align__(16) _Float16 Wscr[4][4608];     // 36,864 B
    __shared__ __align__(16) float gAll[16 * KDIM];      // 8,192 B  exp(em) rows t0..t0+15

    const int t0 = c * CH_L + 1;
    const float* emb = em + (size_t)b * TLEN * KDIM;

    // ---- stage F (transposed exp(trans)); coalesced reads, 2-way-free writes ----
    {
        const int m = tid & 127, kh = tid >> 7;          // k range [kh*64, kh*64+64)
        #pragma unroll
        for (int kk = 0; kk < 8; ++kk) {
            const int k0 = kh * 64 + kk * 8;
            half8 o;
            #pragma unroll
            for (int j = 0; j < 8; ++j)
                o[j] = (_Float16)__expf(trans[(k0 + j) * KDIM + m]);
            *(half8*)&Flds[m * 136 + k0] = o;
        }
    }
    // ---- stage g = exp(em[t0 .. t0+15]) (raw exp; scale handled per-column) ----
    {
        const int i8 = tid * 8;
        const float4 e0 = *(const float4*)&emb[t0 * KDIM + i8];
        const float4 e1 = *(const float4*)&emb[t0 * KDIM + i8 + 4];
        float4 g0, g1;
        g0.x = __expf(e0.x); g0.y = __expf(e0.y); g0.z = __expf(e0.z); g0.w = __expf(e0.w);
        g1.x = __expf(e1.x); g1.y = __expf(e1.y); g1.z = __expf(e1.z); g1.w = __expf(e1.w);
        *(float4*)&gAll[i8] = g0;
        *(float4*)&gAll[i8 + 4] = g1;
    }
    __syncthreads();                                     // the ONLY barrier

    _Float16* Wb = Wscr[w];
    float sc0, sc1;                                      // per-column log scales
    half8 Bf[4][2];                                      // B operand in registers

    // ---- init B = diag(g_{t0}) * F, column-normalized ----
    {
        float tv[4][2][8];
        float cm0 = 0.f, cm1 = 0.f;
        #pragma unroll
        for (int kt = 0; kt < 4; ++kt) {
            const int r0 = kt * 32 + quad * 8;
            const float4 ga = *(const float4*)&gAll[r0];
            const float4 gb = *(const float4*)&gAll[r0 + 4];
            const float gg[8] = {ga.x, ga.y, ga.z, ga.w, gb.x, gb.y, gb.z, gb.w};
            #pragma unroll
            for (int nt = 0; nt < 2; ++nt) {
                const int n = 32 * w + nt * 16 + lm;
                const float4 ta = *(const float4*)&trans[(size_t)n * KDIM + r0];
                const float4 tb = *(const float4*)&trans[(size_t)n * KDIM + r0 + 4];
                const float tt[8] = {ta.x, ta.y, ta.z, ta.w, tb.x, tb.y, tb.z, tb.w};
                float mx = 0.f;
                #pragma unroll
                for (int j = 0; j < 8; ++j) {
                    const float v = __expf(tt[j]) * gg[j];
                    tv[kt][nt][j] = v;
                    mx = fmaxf(mx, v);
                }
                if (nt == 0) cm0 = fmaxf(cm0, mx); else cm1 = fmaxf(cm1, mx);
            }
        }
        cm0 = fmaxf(cm0, __shfl_xor(cm0, 16));
        cm0 = fmaxf(cm0, __shfl_xor(cm0, 32));
        cm1 = fmaxf(cm1, __shfl_xor(cm1, 16));
        cm1 = fmaxf(cm1, __shfl_xor(cm1, 32));
        const float ri0 = 1.0f / cm0, ri1 = 1.0f / cm1;
        sc0 = __logf(cm0);
        sc1 = __logf(cm1);
        #pragma unroll
        for (int kt = 0; kt < 4; ++kt)
            #pragma unroll
            for (int nt = 0; nt < 2; ++nt) {
                const float ri = nt ? ri1 : ri0;
                #pragma unroll
                for (int j = 0; j < 8; ++j)
                    Bf[kt][nt][j] = (_Float16)(tv[kt][nt][j] * ri);
            }
    }

    const floatx4 z4 = {0.f, 0.f, 0.f, 0.f};
    for (int it = 1; it < 16; ++it) {
        floatx4 acc[8][2];
        // kt = 0 with zero-C (no acc zero-fill pass)
        #pragma unroll
        for (int mt = 0; mt < 8; ++mt) {
            const half8 Af = *(const half8*)&Flds[lm * 136 + quad * 8 + mt * 2176];
            acc[mt][0] = __builtin_amdgcn_mfma_f32_16x16x32_f16(Af, Bf[0][0], z4, 0, 0, 0);
            acc[mt][1] = __builtin_amdgcn_mfma_f32_16x16x32_f16(Af, Bf[0][1], z4, 0, 0, 0);
        }
        #pragma unroll
        for (int kt = 1; kt < 4; ++kt) {
            #pragma unroll
            for (int mt = 0; mt < 8; ++mt) {
                const half8 Af = *(const half8*)&Flds[lm * 136 + quad * 8 + mt * 2176 + kt * 32];
                acc[mt][0] = __builtin_amdgcn_mfma_f32_16x16x32_f16(Af, Bf[kt][0], acc[mt][0], 0, 0, 0);
                acc[mt][1] = __builtin_amdgcn_mfma_f32_16x16x32_f16(Af, Bf[kt][1], acc[mt][1], 0, 0, 0);
            }
        }
        // row-scale by g_t, per-column max (wave-local)
        const float* g = &gAll[it * KDIM];
        float cm0 = 0.f, cm1 = 0.f;
        #pragma unroll
        for (int mt = 0; mt < 8; ++mt) {
            const float4 gv = *(const float4*)&g[mt * 16 + quad * 4];  // broadcast in quad
            floatx4 v0 = acc[mt][0], v1 = acc[mt][1];
            v0.x *= gv.x; v0.y *= gv.y; v0.z *= gv.z; v0.w *= gv.w;
            v1.x *= gv.x; v1.y *= gv.y; v1.z *= gv.z; v1.w *= gv.w;
            acc[mt][0] = v0; acc[mt][1] = v1;
            cm0 = fmaxf(cm0, fmaxf(fmaxf(v0.x, v0.y), fmaxf(v0.z, v0.w)));
            cm1 = fmaxf(cm1, fmaxf(fmaxf(v1.x, v1.y), fmaxf(v1.z, v1.w)));
        }
        cm0 = fmaxf(cm0, __shfl_xor(cm0, 16));
        cm0 = fmaxf(cm0, __shfl_xor(cm0, 32));
        cm1 = fmaxf(cm1, __shfl_xor(cm1, 16));
        cm1 = fmaxf(cm1, __shfl_xor(cm1, 32));
        const float ri0 = 1.0f / cm0, ri1 = 1.0f / cm1;
        sc0 += __logf(cm0);
        sc1 += __logf(cm1);

        if (it < 15) {
            // C -> B relayout through PRIVATE LDS (same-wave DS ordering; no barrier)
            #pragma unroll
            for (int mt = 0; mt < 8; ++mt)
                #pragma unroll
                for (int nt = 0; nt < 2; ++nt) {
                    const floatx4 v = acc[mt][nt];
                    const float ri = nt ? ri1 : ri0;
                    half4 o;
                    o[0] = (_Float16)(v.x * ri);
                    o[1] = (_Float16)(v.y * ri);
                    o[2] = (_Float16)(v.z * ri);
                    o[3] = (_Float16)(v.w * ri);
                    *(half4*)&Wb[lm * 136 + quad * 4 + nt * 2176 + mt * 16] = o;
                }
            asm volatile("s_waitcnt lgkmcnt(0)" ::: "memory");
            #pragma unroll
            for (int kt = 0; kt < 4; ++kt)
                #pragma unroll
                for (int nt = 0; nt < 2; ++nt)
                    Bf[kt][nt] = *(const half8*)&Wb[lm * 136 + quad * 8 + nt * 2176 + kt * 32];
        } else {
            // final iteration: write transposed T[m][n_local], stride 36 halfs
            #pragma unroll
            for (int mt = 0; mt < 8; ++mt)
                #pragma unroll
                for (int nt = 0; nt < 2; ++nt) {
                    const floatx4 v = acc[mt][nt];
                    const float ri = nt ? ri1 : ri0;
                    const int ba = quad * 144 + lm + mt * 576 + nt * 16;
                    Wb[ba]       = (_Float16)(v.x * ri);
                    Wb[ba + 36]  = (_Float16)(v.y * ri);
                    Wb[ba + 72]  = (_Float16)(v.z * ri);
                    Wb[ba + 108] = (_Float16)(v.w * ri);
                }
            asm volatile("s_waitcnt lgkmcnt(0)" ::: "memory");
        }
    }

    // epilogue: gather scan-layout units (8 enters x 1 exit, 16B) + coalesced store
    _Float16* Pc = Pst + ((size_t)(b * NMAT + c)) * 16384;
    #pragma unroll
    for (int Kl = 0; Kl < 4; ++Kl)
        #pragma unroll
        for (int h = 0; h < 2; ++h) {
            const half4 lo = *(const half4*)&Wb[(2 * lane + h) * 36 + Kl * 8];
            const half4 hi = *(const half4*)&Wb[(2 * lane + h) * 36 + Kl * 8 + 4];
            half8 v;
            #pragma unroll
            for (int e = 0; e < 4; ++e) { v[e] = lo[e]; v[4 + e] = hi[e]; }
            const int u = (2 * (4 * w + Kl) + h) * 64 + lane;
            *(half8*)&Pc[(size_t)u * 8] = v;
        }
    if (quad == 0) {
        float* sp = Svec + ((size_t)(b * NMAT + c)) * KDIM + 32 * w;
        sp[lm] = sc0;
        sp[lm + 16] = sc1;
    }
}

// ============ kernel 2 (NEW): scan with per-column scales =====================
// Same DMA-double-buffered structure as validated scanw2; p' = exp(lq + s - M)
// with M = wave max, so p' <= 1 always (removes the old sigma-normalization
// f16-overflow exposure). Invariant: true log-alpha_enter = L + lq.
__global__ __launch_bounds__(64, 1) void crf_scanw3(
    const float* __restrict__ em, const _Float16* __restrict__ Pst,
    const float* __restrict__ Svec, float* __restrict__ aEnter)
{
    const int b = blockIdx.x;
    const int lane = threadIdx.x;
    const int j0 = 2 * lane;

    __shared__ __align__(16) _Float16 Pbuf[2][16384];  // 64 KB double buffer
    __shared__ __align__(16) _Float16 pbuf[KDIM];

    const _Float16* Pb = Pst + (size_t)b * NMAT * 16384;
    const float* svb = Svec + (size_t)b * NMAT * KDIM;
    float* aeb = aEnter + (size_t)b * NCH * KDIM;

    #pragma unroll
    for (int i = 0; i < 32; ++i)
        gload_lds16(Pb + i * 512 + lane * 8, &Pbuf[0][i * 512]);

    float2 a0 = *(const float2*)&em[(size_t)b * TLEN * KDIM + j0];
    float mx = fmaxf(a0.x, a0.y);
    #pragma unroll
    for (int o = 32; o; o >>= 1) mx = fmaxf(mx, __shfl_xor(mx, o));
    *(float2*)&aeb[j0] = a0;
    float lq0 = a0.x - mx, lq1 = a0.y - mx;
    float L = mx;
    float2 sv = *(const float2*)&svb[j0];

    for (int c = 0; c < NMAT; ++c) {
        const int cb = c & 1, nb = cb ^ 1;

        asm volatile("s_waitcnt vmcnt(0)" ::: "memory");

        if (c + 1 < NMAT) {
            const _Float16* src = Pb + (size_t)(c + 1) * 16384;
            #pragma unroll
            for (int i = 0; i < 32; ++i)
                gload_lds16(src + i * 512 + lane * 8, &Pbuf[nb][i * 512]);
        }

        // fold per-column scales into p; normalize by wave max
        const float v0 = lq0 + sv.x, v1 = lq1 + sv.y;
        float M = fmaxf(v0, v1);
        #pragma unroll
        for (int o = 32; o; o >>= 1) M = fmaxf(M, __shfl_xor(M, o));
        half2t p2;
        p2[0] = (_Float16)__expf(v0 - M);
        p2[1] = (_Float16)__expf(v1 - M);
        ((half2t*)pbuf)[lane] = p2;
        if (c + 1 < NMAT) sv = *(const float2*)&svb[(size_t)(c + 1) * KDIM + j0];

        // ---- matvec: q_j = sum_k p'_k P~[k][j], j = 2l, 2l+1 ----
        float q0 = 0.f, q1 = 0.f;
        #pragma unroll
        for (int K = 0; K < 16; ++K) {
            const float4 wv = *(const float4*)&pbuf[K * 8];
            const half8 c0 = *(const half8*)&Pbuf[cb][((2 * K + 0) * 64 + lane) * 8];
            const half8 c1 = *(const half8*)&Pbuf[cb][((2 * K + 1) * 64 + lane) * 8];
            q0 = dot8(c0, wv, q0);
            q1 = dot8(c1, wv, q1);
        }

        const float base = L + M;
        const float lg0 = __logf(q0), lg1 = __logf(q1);
        float2 st;
        st.x = base + lg0;
        st.y = base + lg1;
        *(float2*)&aeb[(size_t)(c + 1) * KDIM + j0] = st;
        lq0 = lg0;
        lq1 = lg1;
        L = base;
    }
}

// ================= kernel 1 (OLD, hedge path): chunk products ==================
__global__ __launch_bounds__(256, 2) void crf_chunkmat4(
    const float* __restrict__ trans, const float* __restrict__ em,
    _Float16* __restrict__ Pst, float* __restrict__ Sout)
{
    const int c = blockIdx.x;     // 0..NMAT-1
    const int b = blockIdx.y;
    const int tid = threadIdx.x;
    const int w = tid >> 6, lane = tid & 63;
    const int quad = lane >> 4, lm = lane & 15;

    __shared__ __align__(16) _Float16 buf[17408];   // 34.8 KB padded B-layout
    __shared__ __align__(16) float gAll[16 * KDIM]; // 8 KB
    __shared__ float mE[16];
    __shared__ float slotV[4];

    const int t0 = c * CH_L + 1;
    const float* emb = em + (size_t)b * TLEN * KDIM;

    half8 EA[2][4];
    #pragma unroll
    for (int r = 0; r < 2; ++r) {
        const int m = (2 * w + r) * 16 + lm;
        #pragma unroll
        for (int kt = 0; kt < 4; ++kt) {
            #pragma unroll
            for (int i = 0; i < 8; ++i) {
                EA[r][kt][i] = (_Float16)__expf(trans[(kt * 32 + quad * 8 + i) * KDIM + m]);
            }
        }
    }

    #pragma unroll
    for (int s = 0; s < 2; ++s) {
        int i4 = tid + s * 256;
        *(float4*)&gAll[i4 * 4] = *(const float4*)&emb[t0 * KDIM + i4 * 4];
    }
    __syncthreads();

    #pragma unroll
    for (int r2 = 0; r2 < 4; ++r2) {
        const int r = w * 4 + r2;
        float v = fmaxf(gAll[r * KDIM + lane], gAll[r * KDIM + 64 + lane]);
        #pragma unroll
        for (int o = 32; o; o >>= 1) v = fmaxf(v, __shfl_xor(v, o));
        if (lane == 0) mE[r] = v;
    }
    __syncthreads();

    #pragma unroll
    for (int s = 0; s < 8; ++s) {
        int idx = tid + s * 256;
        gAll[idx] = __expf(gAll[idx] - mE[idx >> 7]);
    }
    __syncthreads();

    for (int s = 0; s < 8; ++s) {
        int g = tid + s * 256;
        int row = g >> 4, nl = g & 15;
        int addr = row * 136 + nl * 8;
        int koct = row & 15;
        int n = (row >> 4) * 16 + nl;
        int j0 = koct * 8;
        const float* tr_ = &trans[n * KDIM + j0];
        const float* g0p = &gAll[j0];
        half8 o;
        #pragma unroll
        for (int x = 0; x < 8; ++x) o[x] = (_Float16)(__expf(tr_[x]) * g0p[x]);
        *(half8*)&buf[addr] = o;
    }
    float S = 0.f;
    if (tid == 0) {
        #pragma unroll
        for (int r = 0; r < 16; ++r) S += mE[r];
    }
    __syncthreads();

    floatx4 acc[2][8];

    for (int it = 1; it < 16; ++it) {
        #pragma unroll
        for (int r = 0; r < 2; ++r)
            #pragma unroll
            for (int nt = 0; nt < 8; ++nt)
                acc[r][nt] = (floatx4){0.f, 0.f, 0.f, 0.f};

        #pragma unroll
        for (int kt = 0; kt < 4; ++kt) {
            #pragma unroll
            for (int nt = 0; nt < 8; ++nt) {
                half8 bb = *(const half8*)&buf[(nt * 16 + kt * 4 + quad) * 136 + lm * 8];
                acc[0][nt] = __builtin_amdgcn_mfma_f32_16x16x32_f16(EA[0][kt], bb, acc[0][nt], 0, 0, 0);
                acc[1][nt] = __builtin_amdgcn_mfma_f32_16x16x32_f16(EA[1][kt], bb, acc[1][nt], 0, 0, 0);
            }
        }

        const float* gc = &gAll[it * KDIM];
        const float4 gr0 = *(const float4*)&gc[(2 * w + 0) * 16 + quad * 4];
        const float4 gr1 = *(const float4*)&gc[(2 * w + 1) * 16 + quad * 4];

        float lmax = 0.f;
        #pragma unroll
        for (int nt = 0; nt < 8; ++nt) {
            floatx4 v0 = acc[0][nt], v1 = acc[1][nt];
            float a0 = fmaxf(fmaxf(v0.x * gr0.x, v0.y * gr0.y), fmaxf(v0.z * gr0.z, v0.w * gr0.w));
            float a1 = fmaxf(fmaxf(v1.x * gr1.x, v1.y * gr1.y), fmaxf(v1.z * gr1.z, v1.w * gr1.w));
            lmax = fmaxf(lmax, fmaxf(a0, a1));
        }
        #pragma unroll
        for (int o = 32; o; o >>= 1) lmax = fmaxf(lmax, __shfl_xor(lmax, o));
        if (lane == 0) slotV[w] = lmax;
        __syncthreads();

        const float rr = fmaxf(fmaxf(slotV[0], slotV[1]), fmaxf(slotV[2], slotV[3]));
        const float rinv = 1.0f / rr;
        if (tid == 0) S += __logf(rr);

        const float4 s0 = {gr0.x * rinv, gr0.y * rinv, gr0.z * rinv, gr0.w * rinv};
        const float4 s1 = {gr1.x * rinv, gr1.y * rinv, gr1.z * rinv, gr1.w * rinv};
        const int jlb = (quad & 1) * 4;
        #pragma unroll
        for (int r = 0; r < 2; ++r) {
            const int tr = 2 * w + r;
            const int kh = tr * 2 + (quad >> 1);
            const float4 sc = r ? s1 : s0;
            #pragma unroll
            for (int nt = 0; nt < 8; ++nt) {
                const floatx4 v = acc[r][nt];
                half4 o;
                o[0] = (_Float16)(v.x * sc.x);
                o[1] = (_Float16)(v.y * sc.y);
                o[2] = (_Float16)(v.z * sc.z);
                o[3] = (_Float16)(v.w * sc.w);
                *(half4*)&buf[(nt * 16 + kh) * 136 + lm * 8 + jlb] = o;
            }
        }
        __syncthreads();
    }

    _Float16* Pc = Pst + ((size_t)(b * NMAT + c)) * 16384;
    for (int s = 0; s < 8; ++s) {
        int u = tid + s * 256;
        int l = u & 63;
        int rh = u >> 6;
        int K = rh >> 1, h = rh & 1;
        int j = 2 * l + h;
        const int base = ((K >> 1) * 16 + (j >> 3)) * 136 + (K & 1) * 64 + (j & 7);
        half8 v;
        #pragma unroll
        for (int e = 0; e < 8; ++e) v[e] = buf[base + e * 8];
        *(half8*)&Pc[u * 8] = v;
    }
    if (tid == 0) Sout[b * NMAT + c] = S;
}

// ================= kernel 2 (OLD, hedge path): scan ===========================
__global__ __launch_bounds__(64, 1) void crf_scanw2(
    const float* __restrict__ em, const _Float16* __restrict__ Pst,
    const float* __restrict__ S, float* __restrict__ aEnter)
{
    const int b = blockIdx.x;
    const int lane = threadIdx.x;
    const int j0 = 2 * lane;

    __shared__ __align__(16) _Float16 Pbuf[2][16384];
    __shared__ __align__(16) _Float16 pbuf[KDIM];
    __shared__ float Sl[NMAT];

    const _Float16* Pb = Pst + (size_t)b * NMAT * 16384;
    float* aeb = aEnter + (size_t)b * NCH * KDIM;

    #pragma unroll
    for (int i = 0; i < 32; ++i)
        gload_lds16(Pb + i * 512 + lane * 8, &Pbuf[0][i * 512]);

    if (lane < NMAT) Sl[lane] = S[b * NMAT + lane];

    float2 a0 = *(const float2*)&em[(size_t)b * TLEN * KDIM + j0];
    float mx = fmaxf(a0.x, a0.y);
    #pragma unroll
    for (int o = 32; o; o >>= 1) mx = fmaxf(mx, __shfl_xor(mx, o));
    float L = mx;
    *(float2*)&aeb[j0] = a0;
    {
        half2t p2;
        p2[0] = (_Float16)__expf(a0.x - L);
        p2[1] = (_Float16)__expf(a0.y - L);
        ((half2t*)pbuf)[lane] = p2;
    }

    for (int c = 0; c < NMAT; ++c) {
        const int cb = c & 1, nb = cb ^ 1;

        asm volatile("s_waitcnt vmcnt(0)" ::: "memory");

        if (c + 1 < NMAT) {
            const _Float16* src = Pb + (size_t)(c + 1) * 16384;
            #pragma unroll
            for (int i = 0; i < 32; ++i)
                gload_lds16(src + i * 512 + lane * 8, &Pbuf[nb][i * 512]);
        }

        float q0 = 0.f, q1 = 0.f;
        #pragma unroll
        for (int K = 0; K < 16; ++K) {
            const float4 w = *(const float4*)&pbuf[K * 8];
            const half8 c0 = *(const half8*)&Pbuf[cb][((2 * K + 0) * 64 + lane) * 8];
            const half8 c1 = *(const half8*)&Pbuf[cb][((2 * K + 1) * 64 + lane) * 8];
            q0 = dot8(c0, w, q0);
            q1 = dot8(c1, w, q1);
        }

        const float s_c = Sl[c];
        const float sigma = __shfl(q0, 0);
        const float base = L + s_c;
        float2 st;
        st.x = base + __logf(q0);
        st.y = base + __logf(q1);
        *(float2*)&aeb[(c + 1) * KDIM + j0] = st;
        const float ri = 1.0f / sigma;
        half2t p2;
        p2[0] = (_Float16)(q0 * ri);
        p2[1] = (_Float16)(q1 * ri);
        ((half2t*)pbuf)[lane] = p2;
        L = base + __logf(sigma);
    }
}

// ================= kernel 3: replayw — one wave per (chunk,batch) =============
__global__ __launch_bounds__(64, 1) void crf_replayw(
    const float* __restrict__ trans, const float* __restrict__ em,
    const int* __restrict__ seq_lens, const float* __restrict__ aEnter,
    float* __restrict__ alpha, float* __restrict__ logZ)
{
    const int c = blockIdx.x, b = blockIdx.y;
    const int l = threadIdx.x;

    __shared__ __align__(16) _Float16 pbuf[KDIM];

    half2t Ea[64], Eb[64];
    #pragma unroll
    for (int t2 = 0; t2 < 64; ++t2) {
        const float* r0 = &trans[(2 * t2) * KDIM];
        const float* r1 = &trans[(2 * t2 + 1) * KDIM];
        half2t ea, eb;
        ea[0] = (_Float16)__expf(r0[l]);
        ea[1] = (_Float16)__expf(r1[l]);
        eb[0] = (_Float16)__expf(r0[l + 64]);
        eb[1] = (_Float16)__expf(r1[l + 64]);
        Ea[t2] = ea;
        Eb[t2] = eb;
    }

    const int len = seq_lens[b];
    const float* emb = em + (size_t)b * TLEN * KDIM;
    float* outb = alpha + (size_t)b * TLEN * KDIM;
    const float* ae = aEnter + ((size_t)b * NCH + c) * KDIM;

    float a0 = ae[l], a1 = ae[l + 64];
    if (c == 0) {
        a0 = emb[l];
        a1 = emb[l + 64];
    }
    float mx = fmaxf(a0, a1);
    #pragma unroll
    for (int o = 32; o; o >>= 1) mx = fmaxf(mx, __shfl_xor(mx, o));
    float L = mx;
    pbuf[l]      = (_Float16)__expf(a0 - L);
    pbuf[l + 64] = (_Float16)__expf(a1 - L);

    float la0 = 0.f, la1 = -INFINITY;
    if (c == 0) {
        outb[l] = a0;
        outb[l + 64] = a1;
        if (len == 1) { la0 = a0; la1 = a1; }
    }

    const int t_begin = c * CH_L + 1;
    const int t_end = (c == NCH - 1) ? (TLEN - 1) : (c * CH_L + CH_L);

    float e0 = emb[t_begin * KDIM + l];
    float e1 = emb[t_begin * KDIM + l + 64];

    for (int t = t_begin; t <= t_end; ++t) {
        float n0 = 0.f, n1 = 0.f;
        if (t < t_end) {
            n0 = emb[(t + 1) * KDIM + l];
            n1 = emb[(t + 1) * KDIM + l + 64];
        }

        float q0 = 0.f, q1 = 0.f;
        #pragma unroll
        for (int s = 0; s < 16; ++s) {
            const float4 w = *(const float4*)&pbuf[s * 8];
            const half2t p0 = __builtin_bit_cast(half2t, w.x);
            const half2t p1 = __builtin_bit_cast(half2t, w.y);
            const half2t p2 = __builtin_bit_cast(half2t, w.z);
            const half2t p3 = __builtin_bit_cast(half2t, w.w);
            q0 = dot2f(p0, Ea[4 * s + 0], q0);
            q0 = dot2f(p1, Ea[4 * s + 1], q0);
            q0 = dot2f(p2, Ea[4 * s + 2], q0);
            q0 = dot2f(p3, Ea[4 * s + 3], q0);
            q1 = dot2f(p0, Eb[4 * s + 0], q1);
            q1 = dot2f(p1, Eb[4 * s + 1], q1);
            q1 = dot2f(p2, Eb[4 * s + 2], q1);
            q1 = dot2f(p3, Eb[4 * s + 3], q1);
        }

        const float A0 = e0 + L + __logf(q0);
        const float A1 = e1 + L + __logf(q1);
        outb[t * KDIM + l] = A0;
        outb[t * KDIM + l + 64] = A1;
        if (t == len - 1) { la0 = A0; la1 = A1; }

        const float sigma = __shfl(q0, 0);
        const float ri = 1.0f / sigma;
        pbuf[l]      = (_Float16)(q0 * ri * __expf(e0));
        pbuf[l + 64] = (_Float16)(q1 * ri * __expf(e1));
        L += __logf(sigma);
        e0 = n0; e1 = n1;
    }

    const bool blockowns = (len == 1) ? (c == 0) : (((len - 2) >> 4) == c);
    if (blockowns) {
        float m2 = fmaxf(la0, la1);
        #pragma unroll
        for (int o = 32; o; o >>= 1) m2 = fmaxf(m2, __shfl_xor(m2, o));
        float e = __expf(la0 - m2) + __expf(la1 - m2);
        #pragma unroll
        for (int o = 32; o; o >>= 1) e += __shfl_xor(e, o);
        if (l == 0) logZ[b] = m2 + __logf(e);
    }
}

// ================= fallback (proven R1 kernel) for small ws =================
__global__ __launch_bounds__(256) void crf_forward_fallback(
    const float* __restrict__ trans, const float* __restrict__ em,
    const int* __restrict__ seq_lens, float* __restrict__ alpha_out,
    float* __restrict__ logZ_out)
{
    const int b = blockIdx.x;
    const int tid = threadIdx.x;
    const int j = tid & (KDIM - 1);
    const int h = tid >> 7;

    __shared__ __align__(16) float p_lds[KDIM];
    __shared__ float part[KDIM];
    __shared__ float red[8];

    float Ereg[64];
    #pragma unroll
    for (int k = 0; k < 64; ++k) Ereg[k] = __expf(trans[(h * 64 + k) * KDIM + j]);

    const int len = seq_lens[b];
    const float* emb = em + (size_t)b * TLEN * KDIM;
    float* outb = alpha_out + (size_t)b * TLEN * KDIM;

    float a = 0.f, last_a = 0.f;
    if (h == 0) {
        a = emb[j];
        outb[j] = a;
        if (len == 1) last_a = a;
    }
    for (int t = 1; t < TLEN; ++t) {
        {
            float v = (h == 0) ? a : -INFINITY;
            #pragma unroll
            for (int o = 32; o >= 1; o >>= 1) v = fmaxf(v, __shfl_xor(v, o));
            if ((tid & 63) == 0) red[tid >> 6] = v;
        }
        __syncthreads();
        const float m = fmaxf(red[0], red[1]);
        if (h == 0) p_lds[j] = __expf(a - m);
        __syncthreads();
        float em_t = 0.f;
        if (h == 0) em_t = emb[t * KDIM + j];
        float acc0 = 0.f, acc1 = 0.f, acc2 = 0.f, acc3 = 0.f;
        const float4* p4 = (const float4*)(p_lds + h * 64);
        #pragma unroll
        for (int k4 = 0; k4 < 16; ++k4) {
            float4 pv = p4[k4];
            acc0 = fmaf(pv.x, Ereg[4 * k4 + 0], acc0);
            acc1 = fmaf(pv.y, Ereg[4 * k4 + 1], acc1);
            acc2 = fmaf(pv.z, Ereg[4 * k4 + 2], acc2);
            acc3 = fmaf(pv.w, Ereg[4 * k4 + 3], acc3);
        }
        const float acc = (acc0 + acc1) + (acc2 + acc3);
        if (h == 1) part[j] = acc;
        __syncthreads();
        if (h == 0) {
            const float q = acc + part[j];
            a = em_t + m + __logf(q);
            outb[t * KDIM + j] = a;
            if (t == len - 1) last_a = a;
        }
    }
    {
        float v = (h == 0) ? last_a : -INFINITY;
        #pragma unroll
        for (int o = 32; o >= 1; o >>= 1) v = fmaxf(v, __shfl_xor(v, o));
        if ((tid & 63) == 0) red[tid >> 6] = v;
    }
    __syncthreads();
    const float m2 = fmaxf(red[0], red[1]);
    float e = (h == 0) ? __expf(last_a - m2) : 0.f;
    #pragma unroll
    for (int o = 32; o >= 1; o >>= 1) e += __shfl_xor(e, o);
    if ((tid & 63) == 0) red[4 + (tid >> 6)] = e;
    __syncthreads();
    if (tid == 0) logZ_out[b] = m2 + logf(red[4] + red[5]);
}

extern "C" void kernel_launch(void* const* d_in, const int* in_sizes, int n_in,
                              void* d_out, int out_size, void* d_ws, size_t ws_size,
                              hipStream_t stream) {
    const float* trans    = (const float*)d_in[0];   // K*K
    const float* em       = (const float*)d_in[1];   // B*T*K
    const int*   seq_lens = (const int*)d_in[2];     // B

    float* alpha_out = (float*)d_out;                            // B*T*K
    float* logZ_out  = alpha_out + (size_t)BATCH * TLEN * KDIM;  // B

    char* ws = (char*)d_ws;

    if (ws_size >= (size_t)WSN_NEED) {
        // NEW path: barrier-free column-parallel chunk products + scaled scan
        _Float16* Pst  = (_Float16*)(ws + WSN_PST);
        float*    Svec = (float*)(ws + WSN_SVEC);
        float*    aEnt = (float*)(ws + WSN_AENT);
        crf_chunkcols<<<dim3(NMAT, BATCH), 256, 0, stream>>>(trans, em, Pst, Svec);
        crf_scanw3<<<BATCH, 64, 0, stream>>>(em, Pst, Svec, aEnt);
        crf_replayw<<<dim3(NCH, BATCH), 64, 0, stream>>>(trans, em, seq_lens, aEnt,
                                                         alpha_out, logZ_out);
    } else if (ws_size >= (size_t)WSO_NEED) {
        // OLD proven path (hedge if workspace is tight for the +252KB Svec)
        _Float16* Pst  = (_Float16*)(ws + WSO_PST);
        float*    Slog = (float*)(ws + WSO_SLOG);
        float*    aEnt = (float*)(ws + WSO_AENT);
        crf_chunkmat4<<<dim3(NMAT, BATCH), 256, 0, stream>>>(trans, em, Pst, Slog);
        crf_scanw2<<<BATCH, 64, 0, stream>>>(em, Pst, Slog, aEnt);
        crf_replayw<<<dim3(NCH, BATCH), 64, 0, stream>>>(trans, em, seq_lens, aEnt,
                                                         alpha_out, logZ_out);
    } else {
        crf_forward_fallback<<<BATCH, 256, 0, stream>>>(trans, em, seq_lens,
                                                        alpha_out, logZ_out);
    }
}

// Round 2
// 156.431 us; speedup vs baseline: 1.0616x; 1.0097x over previous
//
#include <hip/hip_runtime.h>
#include <math.h>

#define KDIM 128
#define TLEN 512
#define BATCH 16
#define CH_L 16
#define NCH 32           // chunks per batch (replay)
#define NMAT 31          // chunk matrices: chunk c covers t in [16c+1, 16c+16]

typedef _Float16 half8 __attribute__((ext_vector_type(8)));
typedef _Float16 half4 __attribute__((ext_vector_type(4)));
typedef _Float16 half2t __attribute__((ext_vector_type(2)));
typedef float floatx4 __attribute__((ext_vector_type(4)));

#if defined(__has_builtin)
#if __has_builtin(__builtin_amdgcn_fdot2)
#define HAVE_FDOT2 1
#endif
#endif

static __device__ __forceinline__ float dot2f(half2t a, half2t b, float c) {
#ifdef HAVE_FDOT2
    return __builtin_amdgcn_fdot2(a, b, c, false);
#else
    return fmaf((float)a[0], (float)b[0], fmaf((float)a[1], (float)b[1], c));
#endif
}

// acc += dot(packed-f16 w (4 VGPRs = 8 halfs), half8 v)
static __device__ __forceinline__ float dot8(const half8 v, const float4 w, float acc) {
    const uint4 r = __builtin_bit_cast(uint4, v);
    acc = dot2f(__builtin_bit_cast(half2t, w.x), __builtin_bit_cast(half2t, r.x), acc);
    acc = dot2f(__builtin_bit_cast(half2t, w.y), __builtin_bit_cast(half2t, r.y), acc);
    acc = dot2f(__builtin_bit_cast(half2t, w.z), __builtin_bit_cast(half2t, r.z), acc);
    acc = dot2f(__builtin_bit_cast(half2t, w.w), __builtin_bit_cast(half2t, r.w), acc);
    return acc;
}

// async global->LDS, 16 B per lane; LDS dest = wave-uniform base + lane*16
static __device__ __forceinline__ void gload_lds16(const _Float16* g, _Float16* l) {
    __builtin_amdgcn_global_load_lds(
        (const __attribute__((address_space(1))) void*)g,
        (__attribute__((address_space(3))) void*)l, 16, 0, 0);
}

// ---------------- workspace layout (bytes) ----------------
// PST : f16 [BATCH][NMAT] chunk products; scan layout: 16B unit u = (2K+h)*64+l
//       holds P[enter=K*8+e][exit=2l+h]
// SVEC: f32 [BATCH][NMAT][128] per-enter-column log scales
#define WSN_PST   0
#define WSN_SVEC  16252928
#define WSN_AENT  16506880
#define WSN_NEED  16769024

// Frag conventions (validated):
//  A-frag tile(mt,kt): lane(quad,lm) holds A[mt*16+lm][kt*32+quad*8 .. +8]
//  B-frag tile(kt,nt): lane(quad,lm) holds B[kt*32+quad*8 .. +8][nt*16+lm]
//  C/D  tile(mt,nt):   lane(quad,lm) reg q = C[mt*16+quad*4+q][nt*16+lm]
//
// ============ kernel 1: column-parallel chunk products, A IN REGISTERS ========
// R1 post-mortem: the loop re-read the loop-invariant A operand from LDS 32x
// per iteration (256 LDS-pipe cyc/wave-iter) -> LDS-bound at MfmaUtil 23%.
// Fix: hoist all 32 A-frags (128 VGPR) into registers once; per-iteration LDS
// traffic drops to the B roundtrip only (8 reads + 16 writes). nt is processed
// as two sequential passes so live state stays ~220 VGPR (Af 128 + Bf 32 +
// acc 32 + temps) under the 256 cap at 2 blocks/CU.
__global__ __launch_bounds__(256, 2) void crf_chunkcols2(
    const float* __restrict__ trans, const float* __restrict__ em,
    _Float16* __restrict__ Pst, float* __restrict__ Svec)
{
    const int c = blockIdx.x;     // 0..NMAT-1
    const int b = blockIdx.y;
    const int tid = threadIdx.x;
    const int w = tid >> 6, lane = tid & 63;
    const int quad = lane >> 4, lm = lane & 15;

    // F[m][k] = exp(trans[k][m]); row stride 136 halfs (272B, 16B aligned)
    __shared__ __align__(16) _Float16 Flds[128 * 136];   // 34,816 B
    // Per-wave scratch: B-layout [n][m] stride 136; final T-layout stride 36
    __shared__ __align__(16) _Float16 Wscr[4][4608];     // 36,864 B
    __shared__ __align__(16) float gAll[16 * KDIM];      // 8,192 B

    const int t0 = c * CH_L + 1;
    const float* emb = em + (size_t)b * TLEN * KDIM;

    // ---- stage F (transposed exp(trans)); coalesced reads ----
    {
        const int m = tid & 127, kh = tid >> 7;
        #pragma unroll
        for (int kk = 0; kk < 8; ++kk) {
            const int k0 = kh * 64 + kk * 8;
            half8 o;
            #pragma unroll
            for (int j = 0; j < 8; ++j)
                o[j] = (_Float16)__expf(trans[(k0 + j) * KDIM + m]);
            *(half8*)&Flds[m * 136 + k0] = o;
        }
    }
    // ---- stage g = exp(em[t0 .. t0+15]) ----
    {
        const int i8 = tid * 8;
        const float4 e0 = *(const float4*)&emb[t0 * KDIM + i8];
        const float4 e1 = *(const float4*)&emb[t0 * KDIM + i8 + 4];
        float4 g0, g1;
        g0.x = __expf(e0.x); g0.y = __expf(e0.y); g0.z = __expf(e0.z); g0.w = __expf(e0.w);
        g1.x = __expf(e1.x); g1.y = __expf(e1.y); g1.z = __expf(e1.z); g1.w = __expf(e1.w);
        *(float4*)&gAll[i8] = g0;
        *(float4*)&gAll[i8 + 4] = g1;
    }
    __syncthreads();                                     // the ONLY barrier

    _Float16* Wb = Wscr[w];
    float sc[2];
    half8 Bf[4][2];

    // ---- init B = diag(g_{t0}) * F, column-normalized (per-nt to cap temps) ----
    #pragma unroll
    for (int nt = 0; nt < 2; ++nt) {
        float tv[4][8];
        float cm = 0.f;
        const int n = 32 * w + nt * 16 + lm;
        #pragma unroll
        for (int kt = 0; kt < 4; ++kt) {
            const int r0 = kt * 32 + quad * 8;
            const float4 ga = *(const float4*)&gAll[r0];
            const float4 gb = *(const float4*)&gAll[r0 + 4];
            const float gg[8] = {ga.x, ga.y, ga.z, ga.w, gb.x, gb.y, gb.z, gb.w};
            const float4 ta = *(const float4*)&trans[(size_t)n * KDIM + r0];
            const float4 tb = *(const float4*)&trans[(size_t)n * KDIM + r0 + 4];
            const float tt[8] = {ta.x, ta.y, ta.z, ta.w, tb.x, tb.y, tb.z, tb.w};
            #pragma unroll
            for (int j = 0; j < 8; ++j) {
                const float v = __expf(tt[j]) * gg[j];
                tv[kt][j] = v;
                cm = fmaxf(cm, v);
            }
        }
        cm = fmaxf(cm, __shfl_xor(cm, 16));
        cm = fmaxf(cm, __shfl_xor(cm, 32));
        const float ri = 1.0f / cm;
        sc[nt] = __logf(cm);
        #pragma unroll
        for (int kt = 0; kt < 4; ++kt)
            #pragma unroll
            for (int j = 0; j < 8; ++j)
                Bf[kt][nt][j] = (_Float16)(tv[kt][j] * ri);
    }

    // ---- hoist all A fragments to registers (one-time 32 ds_read_b128) ----
    half8 Af[8][4];
    #pragma unroll
    for (int mt = 0; mt < 8; ++mt)
        #pragma unroll
        for (int kt = 0; kt < 4; ++kt)
            Af[mt][kt] = *(const half8*)&Flds[lm * 136 + quad * 8 + mt * 2176 + kt * 32];

    const floatx4 z4 = {0.f, 0.f, 0.f, 0.f};
    for (int it = 1; it < 16; ++it) {
        #pragma unroll
        for (int nt = 0; nt < 2; ++nt) {
            floatx4 acc[8];
            #pragma unroll
            for (int mt = 0; mt < 8; ++mt)
                acc[mt] = __builtin_amdgcn_mfma_f32_16x16x32_f16(Af[mt][0], Bf[0][nt], z4, 0, 0, 0);
            #pragma unroll
            for (int kt = 1; kt < 4; ++kt)
                #pragma unroll
                for (int mt = 0; mt < 8; ++mt)
                    acc[mt] = __builtin_amdgcn_mfma_f32_16x16x32_f16(Af[mt][kt], Bf[kt][nt], acc[mt], 0, 0, 0);

            // row-scale by g_t, per-column max (wave-local)
            const float* g = &gAll[it * KDIM];
            float cm = 0.f;
            #pragma unroll
            for (int mt = 0; mt < 8; ++mt) {
                const float4 gv = *(const float4*)&g[mt * 16 + quad * 4];  // quad-broadcast
                floatx4 v = acc[mt];
                v.x *= gv.x; v.y *= gv.y; v.z *= gv.z; v.w *= gv.w;
                acc[mt] = v;
                cm = fmaxf(cm, fmaxf(fmaxf(v.x, v.y), fmaxf(v.z, v.w)));
            }
            cm = fmaxf(cm, __shfl_xor(cm, 16));
            cm = fmaxf(cm, __shfl_xor(cm, 32));
            const float ri = 1.0f / cm;
            sc[nt] += __logf(cm);

            if (it < 15) {
                // C -> B relayout through PRIVATE LDS (same-wave DS order; no barrier)
                #pragma unroll
                for (int mt = 0; mt < 8; ++mt) {
                    const floatx4 v = acc[mt];
                    half4 o;
                    o[0] = (_Float16)(v.x * ri);
                    o[1] = (_Float16)(v.y * ri);
                    o[2] = (_Float16)(v.z * ri);
                    o[3] = (_Float16)(v.w * ri);
                    *(half4*)&Wb[lm * 136 + quad * 4 + nt * 2176 + mt * 16] = o;
                }
            } else {
                // final iteration: transposed T[m][n_local], stride 36 halfs
                #pragma unroll
                for (int mt = 0; mt < 8; ++mt) {
                    const floatx4 v = acc[mt];
                    const int ba = quad * 144 + lm + mt * 576 + nt * 16;
                    Wb[ba]       = (_Float16)(v.x * ri);
                    Wb[ba + 36]  = (_Float16)(v.y * ri);
                    Wb[ba + 72]  = (_Float16)(v.z * ri);
                    Wb[ba + 108] = (_Float16)(v.w * ri);
                }
            }
        }
        asm volatile("s_waitcnt lgkmcnt(0)" ::: "memory");
        if (it < 15) {
            #pragma unroll
            for (int kt = 0; kt < 4; ++kt)
                #pragma unroll
                for (int nt = 0; nt < 2; ++nt)
                    Bf[kt][nt] = *(const half8*)&Wb[lm * 136 + quad * 8 + nt * 2176 + kt * 32];
        }
    }

    // epilogue: gather scan-layout units (8 enters x 1 exit, 16B) + coalesced store
    _Float16* Pc = Pst + ((size_t)(b * NMAT + c)) * 16384;
    #pragma unroll
    for (int Kl = 0; Kl < 4; ++Kl)
        #pragma unroll
        for (int h = 0; h < 2; ++h) {
            const half4 lo = *(const half4*)&Wb[(2 * lane + h) * 36 + Kl * 8];
            const half4 hi = *(const half4*)&Wb[(2 * lane + h) * 36 + Kl * 8 + 4];
            half8 v;
            #pragma unroll
            for (int e = 0; e < 4; ++e) { v[e] = lo[e]; v[4 + e] = hi[e]; }
            const int u = (2 * (4 * w + Kl) + h) * 64 + lane;
            *(half8*)&Pc[(size_t)u * 8] = v;
        }
    if (quad == 0) {
        float* sp = Svec + ((size_t)(b * NMAT + c)) * KDIM + 32 * w;
        sp[lm] = sc[0];
        sp[lm + 16] = sc[1];
    }
}

// ============ kernel 2: scan, triple-buffered DMA with counted vmcnt ==========
// R1 fix: the old double-buffer drained vmcnt(0) each iteration with only one
// chunk of prefetch depth -> each of 31 iterations could eat full load latency.
// Now 3 x 32KB buffers; steady-state wait is vmcnt(32) (chunk c done, chunk
// c+1's 32 loads still in flight), and chunk c+2 is issued before compute.
// p' = exp(lq + s - M), M = wave max -> p' <= 1 (f16-safe).
__global__ __launch_bounds__(64, 1) void crf_scanw4(
    const float* __restrict__ em, const _Float16* __restrict__ Pst,
    const float* __restrict__ Svec, float* __restrict__ aEnter)
{
    const int b = blockIdx.x;
    const int lane = threadIdx.x;
    const int j0 = 2 * lane;

    __shared__ __align__(16) _Float16 Pbuf[3][16384];  // 96 KB triple buffer
    __shared__ __align__(16) _Float16 pbuf[KDIM];

    const _Float16* Pb = Pst + (size_t)b * NMAT * 16384;
    const float* svb = Svec + (size_t)b * NMAT * KDIM;
    float* aeb = aEnter + (size_t)b * NCH * KDIM;

    // prologue: issue chunks 0 and 1
    #pragma unroll
    for (int i = 0; i < 32; ++i)
        gload_lds16(Pb + i * 512 + lane * 8, &Pbuf[0][i * 512]);
    #pragma unroll
    for (int i = 0; i < 32; ++i)
        gload_lds16(Pb + 16384 + i * 512 + lane * 8, &Pbuf[1][i * 512]);

    float2 a0 = *(const float2*)&em[(size_t)b * TLEN * KDIM + j0];
    float mx = fmaxf(a0.x, a0.y);
    #pragma unroll
    for (int o = 32; o; o >>= 1) mx = fmaxf(mx, __shfl_xor(mx, o));
    *(float2*)&aeb[j0] = a0;
    float lq0 = a0.x - mx, lq1 = a0.y - mx;
    float L = mx;
    float2 sv = *(const float2*)&svb[j0];

    int cb = 0;
    for (int c = 0; c < NMAT; ++c) {
        // chunk c complete: all but the most recent 32 loads (chunk c+1) retired
        if (c + 1 < NMAT) {
            asm volatile("s_waitcnt vmcnt(32)" ::: "memory");
        } else {
            asm volatile("s_waitcnt vmcnt(0)" ::: "memory");
        }

        // issue DMA for chunk c+2 (two iterations of slack)
        if (c + 2 < NMAT) {
            const _Float16* src = Pb + (size_t)(c + 2) * 16384;
            _Float16* dst = &Pbuf[(cb + 2) % 3][0];
            #pragma unroll
            for (int i = 0; i < 32; ++i)
                gload_lds16(src + i * 512 + lane * 8, &dst[i * 512]);
        }

        // fold per-column scales into p; normalize by wave max
        const float v0 = lq0 + sv.x, v1 = lq1 + sv.y;
        float M = fmaxf(v0, v1);
        #pragma unroll
        for (int o = 32; o; o >>= 1) M = fmaxf(M, __shfl_xor(M, o));
        half2t p2;
        p2[0] = (_Float16)__expf(v0 - M);
        p2[1] = (_Float16)__expf(v1 - M);
        ((half2t*)pbuf)[lane] = p2;
        if (c + 1 < NMAT) sv = *(const float2*)&svb[(size_t)(c + 1) * KDIM + j0];

        // ---- matvec: q_j = sum_k p'_k P~[k][j], j = 2l, 2l+1 ----
        const _Float16* Pcur = &Pbuf[cb][0];
        float q0 = 0.f, q1 = 0.f;
        #pragma unroll
        for (int K = 0; K < 16; ++K) {
            const float4 wv = *(const float4*)&pbuf[K * 8];
            const half8 c0 = *(const half8*)&Pcur[((2 * K + 0) * 64 + lane) * 8];
            const half8 c1 = *(const half8*)&Pcur[((2 * K + 1) * 64 + lane) * 8];
            q0 = dot8(c0, wv, q0);
            q1 = dot8(c1, wv, q1);
        }

        const float base = L + M;
        const float lg0 = __logf(q0), lg1 = __logf(q1);
        float2 st;
        st.x = base + lg0;
        st.y = base + lg1;
        *(float2*)&aeb[(size_t)(c + 1) * KDIM + j0] = st;
        lq0 = lg0;
        lq1 = lg1;
        L = base;
        cb = (cb + 1) % 3;
    }
}

// ================= kernel 3: replayw — one wave per (chunk,batch) =============
__global__ __launch_bounds__(64, 1) void crf_replayw(
    const float* __restrict__ trans, const float* __restrict__ em,
    const int* __restrict__ seq_lens, const float* __restrict__ aEnter,
    float* __restrict__ alpha, float* __restrict__ logZ)
{
    const int c = blockIdx.x, b = blockIdx.y;
    const int l = threadIdx.x;

    __shared__ __align__(16) _Float16 pbuf[KDIM];

    half2t Ea[64], Eb[64];
    #pragma unroll
    for (int t2 = 0; t2 < 64; ++t2) {
        const float* r0 = &trans[(2 * t2) * KDIM];
        const float* r1 = &trans[(2 * t2 + 1) * KDIM];
        half2t ea, eb;
        ea[0] = (_Float16)__expf(r0[l]);
        ea[1] = (_Float16)__expf(r1[l]);
        eb[0] = (_Float16)__expf(r0[l + 64]);
        eb[1] = (_Float16)__expf(r1[l + 64]);
        Ea[t2] = ea;
        Eb[t2] = eb;
    }

    const int len = seq_lens[b];
    const float* emb = em + (size_t)b * TLEN * KDIM;
    float* outb = alpha + (size_t)b * TLEN * KDIM;
    const float* ae = aEnter + ((size_t)b * NCH + c) * KDIM;

    float a0 = ae[l], a1 = ae[l + 64];
    if (c == 0) {
        a0 = emb[l];
        a1 = emb[l + 64];
    }
    float mx = fmaxf(a0, a1);
    #pragma unroll
    for (int o = 32; o; o >>= 1) mx = fmaxf(mx, __shfl_xor(mx, o));
    float L = mx;
    pbuf[l]      = (_Float16)__expf(a0 - L);
    pbuf[l + 64] = (_Float16)__expf(a1 - L);

    float la0 = 0.f, la1 = -INFINITY;
    if (c == 0) {
        outb[l] = a0;
        outb[l + 64] = a1;
        if (len == 1) { la0 = a0; la1 = a1; }
    }

    const int t_begin = c * CH_L + 1;
    const int t_end = (c == NCH - 1) ? (TLEN - 1) : (c * CH_L + CH_L);

    float e0 = emb[t_begin * KDIM + l];
    float e1 = emb[t_begin * KDIM + l + 64];

    for (int t = t_begin; t <= t_end; ++t) {
        float n0 = 0.f, n1 = 0.f;
        if (t < t_end) {
            n0 = emb[(t + 1) * KDIM + l];
            n1 = emb[(t + 1) * KDIM + l + 64];
        }

        float q0 = 0.f, q1 = 0.f;
        #pragma unroll
        for (int s = 0; s < 16; ++s) {
            const float4 w = *(const float4*)&pbuf[s * 8];
            const half2t p0 = __builtin_bit_cast(half2t, w.x);
            const half2t p1 = __builtin_bit_cast(half2t, w.y);
            const half2t p2 = __builtin_bit_cast(half2t, w.z);
            const half2t p3 = __builtin_bit_cast(half2t, w.w);
            q0 = dot2f(p0, Ea[4 * s + 0], q0);
            q0 = dot2f(p1, Ea[4 * s + 1], q0);
            q0 = dot2f(p2, Ea[4 * s + 2], q0);
            q0 = dot2f(p3, Ea[4 * s + 3], q0);
            q1 = dot2f(p0, Eb[4 * s + 0], q1);
            q1 = dot2f(p1, Eb[4 * s + 1], q1);
            q1 = dot2f(p2, Eb[4 * s + 2], q1);
            q1 = dot2f(p3, Eb[4 * s + 3], q1);
        }

        const float A0 = e0 + L + __logf(q0);
        const float A1 = e1 + L + __logf(q1);
        outb[t * KDIM + l] = A0;
        outb[t * KDIM + l + 64] = A1;
        if (t == len - 1) { la0 = A0; la1 = A1; }

        const float sigma = __shfl(q0, 0);
        const float ri = 1.0f / sigma;
        pbuf[l]      = (_Float16)(q0 * ri * __expf(e0));
        pbuf[l + 64] = (_Float16)(q1 * ri * __expf(e1));
        L += __logf(sigma);
        e0 = n0; e1 = n1;
    }

    const bool blockowns = (len == 1) ? (c == 0) : (((len - 2) >> 4) == c);
    if (blockowns) {
        float m2 = fmaxf(la0, la1);
        #pragma unroll
        for (int o = 32; o; o >>= 1) m2 = fmaxf(m2, __shfl_xor(m2, o));
        float e = __expf(la0 - m2) + __expf(la1 - m2);
        #pragma unroll
        for (int o = 32; o; o >>= 1) e += __shfl_xor(e, o);
        if (l == 0) logZ[b] = m2 + __logf(e);
    }
}

// ================= fallback (proven R1 kernel) for small ws =================
__global__ __launch_bounds__(256) void crf_forward_fallback(
    const float* __restrict__ trans, const float* __restrict__ em,
    const int* __restrict__ seq_lens, float* __restrict__ alpha_out,
    float* __restrict__ logZ_out)
{
    const int b = blockIdx.x;
    const int tid = threadIdx.x;
    const int j = tid & (KDIM - 1);
    const int h = tid >> 7;

    __shared__ __align__(16) float p_lds[KDIM];
    __shared__ float part[KDIM];
    __shared__ float red[8];

    float Ereg[64];
    #pragma unroll
    for (int k = 0; k < 64; ++k) Ereg[k] = __expf(trans[(h * 64 + k) * KDIM + j]);

    const int len = seq_lens[b];
    const float* emb = em + (size_t)b * TLEN * KDIM;
    float* outb = alpha_out + (size_t)b * TLEN * KDIM;

    float a = 0.f, last_a = 0.f;
    if (h == 0) {
        a = emb[j];
        outb[j] = a;
        if (len == 1) last_a = a;
    }
    for (int t = 1; t < TLEN; ++t) {
        {
            float v = (h == 0) ? a : -INFINITY;
            #pragma unroll
            for (int o = 32; o >= 1; o >>= 1) v = fmaxf(v, __shfl_xor(v, o));
            if ((tid & 63) == 0) red[tid >> 6] = v;
        }
        __syncthreads();
        const float m = fmaxf(red[0], red[1]);
        if (h == 0) p_lds[j] = __expf(a - m);
        __syncthreads();
        float em_t = 0.f;
        if (h == 0) em_t = emb[t * KDIM + j];
        float acc0 = 0.f, acc1 = 0.f, acc2 = 0.f, acc3 = 0.f;
        const float4* p4 = (const float4*)(p_lds + h * 64);
        #pragma unroll
        for (int k4 = 0; k4 < 16; ++k4) {
            float4 pv = p4[k4];
            acc0 = fmaf(pv.x, Ereg[4 * k4 + 0], acc0);
            acc1 = fmaf(pv.y, Ereg[4 * k4 + 1], acc1);
            acc2 = fmaf(pv.z, Ereg[4 * k4 + 2], acc2);
            acc3 = fmaf(pv.w, Ereg[4 * k4 + 3], acc3);
        }
        const float acc = (acc0 + acc1) + (acc2 + acc3);
        if (h == 1) part[j] = acc;
        __syncthreads();
        if (h == 0) {
            const float q = acc + part[j];
            a = em_t + m + __logf(q);
            outb[t * KDIM + j] = a;
            if (t == len - 1) last_a = a;
        }
    }
    {
        float v = (h == 0) ? last_a : -INFINITY;
        #pragma unroll
        for (int o = 32; o >= 1; o >>= 1) v = fmaxf(v, __shfl_xor(v, o));
        if ((tid & 63) == 0) red[tid >> 6] = v;
    }
    __syncthreads();
    const float m2 = fmaxf(red[0], red[1]);
    float e = (h == 0) ? __expf(last_a - m2) : 0.f;
    #pragma unroll
    for (int o = 32; o >= 1; o >>= 1) e += __shfl_xor(e, o);
    if ((tid & 63) == 0) red[4 + (tid >> 6)] = e;
    __syncthreads();
    if (tid == 0) logZ_out[b] = m2 + logf(red[4] + red[5]);
}

extern "C" void kernel_launch(void* const* d_in, const int* in_sizes, int n_in,
                              void* d_out, int out_size, void* d_ws, size_t ws_size,
                              hipStream_t stream) {
    const float* trans    = (const float*)d_in[0];   // K*K
    const float* em       = (const float*)d_in[1];   // B*T*K
    const int*   seq_lens = (const int*)d_in[2];     // B

    float* alpha_out = (float*)d_out;                            // B*T*K
    float* logZ_out  = alpha_out + (size_t)BATCH * TLEN * KDIM;  // B

    char* ws = (char*)d_ws;

    if (ws_size >= (size_t)WSN_NEED) {
        _Float16* Pst  = (_Float16*)(ws + WSN_PST);
        float*    Svec = (float*)(ws + WSN_SVEC);
        float*    aEnt = (float*)(ws + WSN_AENT);
        crf_chunkcols2<<<dim3(NMAT, BATCH), 256, 0, stream>>>(trans, em, Pst, Svec);
        crf_scanw4<<<BATCH, 64, 0, stream>>>(em, Pst, Svec, aEnt);
        crf_replayw<<<dim3(NCH, BATCH), 64, 0, stream>>>(trans, em, seq_lens, aEnt,
                                                         alpha_out, logZ_out);
    } else {
        crf_forward_fallback<<<BATCH, 256, 0, stream>>>(trans, em, seq_lens,
                                                        alpha_out, logZ_out);
    }
}